// Round 3
// baseline (1118.114 us; speedup 1.0000x reference)
//
#include <hip/hip_runtime.h>
#include <hip/hip_bf16.h>
#include <hip/hip_cooperative_groups.h>

namespace cg = cooperative_groups;

// Problem constants (fixed by the reference file).
constexpr int N_NODES = 20000;
constexpr int N_EDGES = 640000;
constexpr int D = 128;          // D_IN == D_OUT == 128
constexpr int N_TILES_NODE = (N_NODES + 63) / 64;   // 313
constexpr int N_TILES_EDGE = N_EDGES / 128;         // 5000
constexpr int N_CHUNKS = (N_NODES + 255) / 256;     // 79 (scan chunks)
constexpr int TILE_LD = 33;     // 32 m + 1 pad: conflict-free both ways

typedef float  f32x4  __attribute__((ext_vector_type(4)));
typedef short  short8 __attribute__((ext_vector_type(8)));

// fp32 -> bf16 bits, round-to-nearest-even (scalar)
__device__ inline short f2bf(float f) {
    unsigned u = __builtin_bit_cast(unsigned, f);
    u += 0x7fffu + ((u >> 16) & 1u);
    return (short)(u >> 16);
}
__device__ inline float bf2f(short s) {
    unsigned u = ((unsigned)(unsigned short)s) << 16;
    return __builtin_bit_cast(float, u);
}
// packed fp32x2 -> bf16x2 (RNE), single HW instruction
__device__ inline unsigned cvt_pk_bf16(float a, float b) {
    unsigned r;
    asm("v_cvt_pk_bf16_f32 %0, %1, %2" : "=v"(r) : "v"(a), "v"(b));
    return r;
}

// ---------------------------------------------------------------------------
// Device bodies (shared between the cooperative mega-kernel and the fallback).
// ---------------------------------------------------------------------------

// One 8-column chunk of the weight-fragment prep.  t in [0, 2048).
__device__ __forceinline__ void prep_chunk(
    int t, const float* __restrict__ We, const float* __restrict__ Wn,
    short8* __restrict__ fragE, short8* __restrict__ fragH, short8* __restrict__ fragL)
{
    const int n = t >> 4, k8 = t & 15;              // row n, 8-col group k8
    const int kt = k8 >> 2, q = k8 & 3;
    const int fi = ((n >> 4) * 4 + kt) * 64 + q * 16 + (n & 15);

    {
        const float4 x = *(const float4*)(We + n * D + k8 * 8);
        const float4 y = *(const float4*)(We + n * D + k8 * 8 + 4);
        short8 s;
        unsigned* sp = (unsigned*)&s;
        sp[0] = cvt_pk_bf16(x.x, x.y);
        sp[1] = cvt_pk_bf16(x.z, x.w);
        sp[2] = cvt_pk_bf16(y.x, y.y);
        sp[3] = cvt_pk_bf16(y.z, y.w);
        fragE[fi] = s;
    }
    {
        const float4 x = *(const float4*)(Wn + n * D + k8 * 8);
        const float4 y = *(const float4*)(Wn + n * D + k8 * 8 + 4);
        const float v[8] = {x.x, x.y, x.z, x.w, y.x, y.y, y.z, y.w};
        short8 hi, lo;
        #pragma unroll
        for (int j = 0; j < 8; ++j) {
            hi[j] = f2bf(v[j]);
            lo[j] = f2bf(v[j] - bf2f(hi[j]));
        }
        fragH[fi] = hi;
        fragL[fi] = lo;
    }
}

// One 64-row node tile: h = nf @ Wn.T + bn (hi/lo bf16 split, ~fp32 exact),
// h -> workspace; out = relu(h + res_w) / degs (residual init).
__device__ __forceinline__ void node_tile(
    int tb, int tid,
    const float* __restrict__ nf, const float* __restrict__ degs,
    const short8* __restrict__ fragH, const short8* __restrict__ fragL,
    const float* __restrict__ bn, const float* __restrict__ res_w,
    float* __restrict__ h_ws, float* __restrict__ out)
{
    const int lane = tid & 63, wave = tid >> 6;
    const int quad = lane >> 4, row16 = lane & 15;
    const int mbase = tb * 64 + wave * 16;

    const int arow = min(mbase + row16, N_NODES - 1);
    short8 ah[4], al[4];
    const float* p = nf + arow * D + quad * 8;
    #pragma unroll
    for (int kt = 0; kt < 4; ++kt) {
        const float4 x = *(const float4*)(p + kt * 32);
        const float4 y = *(const float4*)(p + kt * 32 + 4);
        const float v[8] = {x.x, x.y, x.z, x.w, y.x, y.y, y.z, y.w};
        #pragma unroll
        for (int j = 0; j < 8; ++j) {
            ah[kt][j] = f2bf(v[j]);
            al[kt][j] = f2bf(v[j] - bf2f(ah[kt][j]));
        }
    }

    int   orow[4];
    float dinv[4];
    #pragma unroll
    for (int r = 0; r < 4; ++r) {
        orow[r] = mbase + quad * 4 + r;
        dinv[r] = 1.0f / degs[min(orow[r], N_NODES - 1)];
    }

    #pragma unroll
    for (int nt = 0; nt < 8; ++nt) {
        f32x4 acc = {0.f, 0.f, 0.f, 0.f};
        #pragma unroll
        for (int kt = 0; kt < 4; ++kt) {
            const short8 bh = fragH[(nt * 4 + kt) * 64 + lane];
            const short8 bl = fragL[(nt * 4 + kt) * 64 + lane];
            acc = __builtin_amdgcn_mfma_f32_16x16x32_bf16(al[kt], bh, acc, 0, 0, 0);
            acc = __builtin_amdgcn_mfma_f32_16x16x32_bf16(ah[kt], bl, acc, 0, 0, 0);
            acc = __builtin_amdgcn_mfma_f32_16x16x32_bf16(ah[kt], bh, acc, 0, 0, 0);
        }
        const int col = nt * 16 + row16;
        const float bnv = bn[col], rwv = res_w[col];
        #pragma unroll
        for (int r = 0; r < 4; ++r) {
            if (orow[r] < N_NODES) {
                const float hv = acc[r] + bnv;
                h_ws[orow[r] * D + col] = hv;
                out[orow[r] * D + col] = fmaxf(hv + rwv, 0.0f) * dinv[r];
            }
        }
    }
}

// One 128-edge tile (dst-sorted order): e = ef[perm] @ We.T + be (bf16 MFMA),
// msg = norm * relu(h[src] + e), segmented sum over sorted-dst runs.
// tile/sdst/sperm slices are strictly wave-private -> no __syncthreads.
// perm is staged in LDS (one coalesced 32-lane load) so A-row indices and
// epilogue metadata come from LDS instead of redundant global loads.
__device__ __forceinline__ void edge_tile(
    int tb, int tid, float* __restrict__ tileB, int* __restrict__ sdstB,
    int* __restrict__ spermB,
    const float* __restrict__ ef, const float* __restrict__ norm,
    const int* __restrict__ src, const int* __restrict__ perm,
    const int* __restrict__ dsts, const short8* __restrict__ fragE,
    const float* __restrict__ be, const float* __restrict__ h,
    float* __restrict__ out)
{
    const int lane  = tid & 63;
    const int quad  = lane >> 4;
    const int row16 = lane & 15;
    const int wave  = tid >> 6;
    const int p0 = tb * 128 + wave * 32;       // 32 sorted positions/wave

    float* tw = tileB + wave * (32 * TILE_LD);
    int*   sw = sdstB + wave * 32;
    int*   pw = spermB + wave * 32;

    if (lane < 32) {
        sw[lane] = dsts[p0 + lane];
        pw[lane] = perm[p0 + lane];
    }

    // A fragments: gather edge rows (indices from LDS), fp32 -> bf16
    short8 afr[2][4];
    #pragma unroll
    for (int mt = 0; mt < 2; ++mt) {
        const int erow = pw[mt * 16 + row16];
        const float* p = ef + erow * D + quad * 8;
        #pragma unroll
        for (int kt = 0; kt < 4; ++kt) {
            const float4 x = *(const float4*)(p + kt * 32);
            const float4 y = *(const float4*)(p + kt * 32 + 4);
            short8 a;
            unsigned* ap = (unsigned*)&a;
            ap[0] = cvt_pk_bf16(x.x, x.y);
            ap[1] = cvt_pk_bf16(x.z, x.w);
            ap[2] = cvt_pk_bf16(y.x, y.y);
            ap[3] = cvt_pk_bf16(y.z, y.w);
            afr[mt][kt] = a;
        }
    }

    // Edge metadata for epilogue rows this lane owns (indices from LDS)
    int   sidx[2][4];
    float nrm[2][4];
    #pragma unroll
    for (int mt = 0; mt < 2; ++mt) {
        #pragma unroll
        for (int r = 0; r < 4; ++r) {
            const int pe = pw[mt * 16 + quad * 4 + r];
            sidx[mt][r] = src[pe];
            nrm[mt][r]  = norm[pe];
        }
    }

    for (int g = 0; g < 4; ++g) {
        #pragma unroll
        for (int t2 = 0; t2 < 2; ++t2) {
            const int nt = g * 2 + t2;
            short8 bfr[4];
            #pragma unroll
            for (int kt = 0; kt < 4; ++kt)
                bfr[kt] = fragE[(nt * 4 + kt) * 64 + lane];

            f32x4 acc0 = {0.f, 0.f, 0.f, 0.f};
            f32x4 acc1 = {0.f, 0.f, 0.f, 0.f};
            #pragma unroll
            for (int kt = 0; kt < 4; ++kt) {
                acc0 = __builtin_amdgcn_mfma_f32_16x16x32_bf16(afr[0][kt], bfr[kt], acc0, 0, 0, 0);
                acc1 = __builtin_amdgcn_mfma_f32_16x16x32_bf16(afr[1][kt], bfr[kt], acc1, 0, 0, 0);
            }

            const int col = nt * 16 + row16;
            const float bev = be[col];
            float* tp = tw + (t2 * 16 + row16) * TILE_LD;
            #pragma unroll
            for (int r = 0; r < 4; ++r) {
                const int m0 = quad * 4 + r;
                const float hv0 = h[sidx[0][r] * D + col];
                tp[m0] = nrm[0][r] * fmaxf(hv0 + acc0[r] + bev, 0.0f);
                const int m1 = m0 + 16;
                const float hv1 = h[sidx[1][r] * D + col];
                tp[m1] = nrm[1][r] * fmaxf(hv1 + acc1[r] + bev, 0.0f);
            }
        }

        // segmented scan: lane = col*2 + chunk; chunk covers 16 sorted rows.
        {
            const int c = lane >> 1;
            const int chunk = lane & 1;
            const int mbeg = chunk * 16;
            const float* sp = tw + c * TILE_LD;
            const int gcol = g * 32 + c;
            int cur = sw[mbeg];
            float sum = 0.0f;
            #pragma unroll
            for (int m = mbeg; m < mbeg + 16; ++m) {
                const int dm = sw[m];
                const float v = sp[m];
                if (dm != cur) {
                    atomicAdd(&out[cur * D + gcol], sum);
                    sum = 0.0f;
                    cur = dm;
                }
                sum += v;
            }
            atomicAdd(&out[cur * D + gcol], sum);
        }
    }
}

// 64-lane inclusive scan via shfl_up
__device__ __forceinline__ int scan64(int v, int lane) {
    #pragma unroll
    for (int off = 1; off < 64; off <<= 1) {
        const int nbr = __shfl_up(v, off, 64);
        if (lane >= off) v += nbr;
    }
    return v;
}

// ---------------------------------------------------------------------------
// Cooperative mega-kernel, __launch_bounds__(256,4): <=128 VGPR -> 4 blocks/CU
// (16 waves/CU) -- the R2 run showed 188 VGPR / 2 blocks/CU starved the
// latency-bound gather phases (Occupancy 11.9%, HBM 13.8%).
// Phases: P0 zero+prep | P1 hist | P2a local scans | P2b block-sum scan |
//         P2c add offsets | P3 scatter+node | P4 edge
// ---------------------------------------------------------------------------
__global__ __launch_bounds__(256, 4) void mega_kernel(
    const float* __restrict__ nf, const float* __restrict__ ef,
    const float* __restrict__ degs, const float* __restrict__ norm,
    const int* __restrict__ src, const int* __restrict__ dst,
    const float* __restrict__ Wn, const float* __restrict__ bn,
    const float* __restrict__ We, const float* __restrict__ be,
    const float* __restrict__ res_w,
    float* __restrict__ out, float* __restrict__ h_ws,
    int* __restrict__ perm, int* __restrict__ dsts, int* __restrict__ count,
    int* __restrict__ bsum,
    short8* __restrict__ fragE, short8* __restrict__ fragH, short8* __restrict__ fragL)
{
    cg::grid_group gg = cg::this_grid();

    __shared__ float tile[4][32 * TILE_LD];   // 16896 B (edge phase)
    __shared__ int   sdst[4][32];             // 512 B   (edge phase)
    __shared__ int   sperm[4][32];            // 512 B   (edge phase)
    __shared__ int   wsum[4];                 // scan phase

    const int tid  = threadIdx.x;
    const int gtid = blockIdx.x * 256 + tid;
    const int gsz  = gridDim.x * 256;
    const int lane = tid & 63, w = tid >> 6;

    // ---- P0: zero histogram + build weight fragments
    for (int i = gtid; i < N_NODES; i += gsz) count[i] = 0;
    for (int t = gtid; t < 2048; t += gsz)
        prep_chunk(t, We, Wn, fragE, fragH, fragL);
    gg.sync();

    // ---- P1: histogram of dst
    for (int e = gtid; e < N_EDGES; e += gsz) atomicAdd(&count[dst[e]], 1);
    gg.sync();

    // ---- P2a: per-chunk (256-elem) local exclusive scans, chunk totals->bsum
    if (blockIdx.x < N_CHUNKS) {
        const int idx = blockIdx.x * 256 + tid;
        const int v = (idx < N_NODES) ? count[idx] : 0;
        const int incl = scan64(v, lane);
        if (lane == 63) wsum[w] = incl;
        __syncthreads();
        int woff = 0;
        #pragma unroll
        for (int j = 0; j < 4; ++j) if (j < w) woff += wsum[j];
        if (idx < N_NODES) count[idx] = woff + incl - v;
        if (tid == 255) bsum[blockIdx.x] = woff + incl;   // chunk total
    }
    gg.sync();

    // ---- P2b: exclusive scan of the 79 chunk totals (block 0, wave 0)
    if (blockIdx.x == 0 && tid < 64) {
        const int b0 = (tid < N_CHUNKS) ? bsum[tid] : 0;
        const int i0 = scan64(b0, tid);
        const int t0 = __shfl(i0, 63, 64);
        const int b1 = (64 + tid < N_CHUNKS) ? bsum[64 + tid] : 0;
        const int i1 = scan64(b1, tid);
        if (tid < N_CHUNKS) bsum[tid] = i0 - b0;
        if (64 + tid < N_CHUNKS) bsum[64 + tid] = t0 + i1 - b1;
    }
    gg.sync();

    // ---- P2c: add chunk offsets -> final exclusive prefix (cursor)
    if (blockIdx.x < N_CHUNKS) {
        const int idx = blockIdx.x * 256 + tid;
        if (idx < N_NODES) count[idx] += bsum[blockIdx.x];
    }
    gg.sync();

    // ---- P3: scatter (cursor = scanned count) + node path, overlapped
    for (int e = gtid; e < N_EDGES; e += gsz) {
        const int d = dst[e];
        const int pos = atomicAdd(&count[d], 1);
        perm[pos] = e;
        dsts[pos] = d;
    }
    for (int tb = blockIdx.x; tb < N_TILES_NODE; tb += gridDim.x)
        node_tile(tb, tid, nf, degs, fragH, fragL, bn, res_w, h_ws, out);
    gg.sync();

    // ---- P4: edge path
    for (int tb = blockIdx.x; tb < N_TILES_EDGE; tb += gridDim.x)
        edge_tile(tb, tid, &tile[0][0], &sdst[0][0], &sperm[0][0],
                  ef, norm, src, perm, dsts, fragE, be, h_ws, out);
}

// ---------------------------------------------------------------------------
// Non-cooperative fallback, reusing the same bodies.
// ---------------------------------------------------------------------------
__global__ __launch_bounds__(256) void fb_prep(
    const float* __restrict__ We, const float* __restrict__ Wn,
    short8* __restrict__ fragE, short8* __restrict__ fragH,
    short8* __restrict__ fragL, int* __restrict__ count)
{
    const int t = blockIdx.x * 256 + threadIdx.x;
    for (int i = t; i < N_NODES; i += 2048) count[i] = 0;
    prep_chunk(t, We, Wn, fragE, fragH, fragL);
}

__global__ __launch_bounds__(256) void fb_hist(
    const int* __restrict__ dst, int* __restrict__ count)
{
    const int e = blockIdx.x * 256 + threadIdx.x;
    if (e < N_EDGES) atomicAdd(&count[dst[e]], 1);
}

__global__ __launch_bounds__(256) void fb_scan(int* __restrict__ count)
{
    __shared__ int wsum[4];
    const int tid = threadIdx.x;
    const int lane = tid & 63, w = tid >> 6;
    int carry = 0;
    for (int base = 0; base < N_NODES; base += 256) {
        const int idx = base + tid;
        const int v = (idx < N_NODES) ? count[idx] : 0;
        const int incl = scan64(v, lane);
        if (lane == 63) wsum[w] = incl;
        __syncthreads();
        int woff = 0;
        #pragma unroll
        for (int j = 0; j < 4; ++j) if (j < w) woff += wsum[j];
        const int tot = wsum[0] + wsum[1] + wsum[2] + wsum[3];
        if (idx < N_NODES) count[idx] = carry + woff + incl - v;
        carry += tot;
        __syncthreads();
    }
}

__global__ __launch_bounds__(256) void fb_scatter(
    const int* __restrict__ dst, int* __restrict__ cursor,
    int* __restrict__ perm, int* __restrict__ dsts)
{
    const int e = blockIdx.x * 256 + threadIdx.x;
    if (e < N_EDGES) {
        const int d = dst[e];
        const int pos = atomicAdd(&cursor[d], 1);
        perm[pos] = e;
        dsts[pos] = d;
    }
}

__global__ __launch_bounds__(256) void fb_node(
    const float* __restrict__ nf, const float* __restrict__ degs,
    const short8* __restrict__ fragH, const short8* __restrict__ fragL,
    const float* __restrict__ bn, const float* __restrict__ res_w,
    float* __restrict__ h_ws, float* __restrict__ out)
{
    node_tile(blockIdx.x, threadIdx.x, nf, degs, fragH, fragL, bn, res_w, h_ws, out);
}

__global__ __launch_bounds__(256, 4) void fb_edge(
    const float* __restrict__ ef, const float* __restrict__ norm,
    const int* __restrict__ src, const int* __restrict__ perm,
    const int* __restrict__ dsts, const short8* __restrict__ fragE,
    const float* __restrict__ be, const float* __restrict__ h,
    float* __restrict__ out)
{
    __shared__ float tile[4][32 * TILE_LD];
    __shared__ int   sdst[4][32];
    __shared__ int   sperm[4][32];
    edge_tile(blockIdx.x, threadIdx.x, &tile[0][0], &sdst[0][0], &sperm[0][0],
              ef, norm, src, perm, dsts, fragE, be, h, out);
}

extern "C" void kernel_launch(void* const* d_in, const int* in_sizes, int n_in,
                              void* d_out, int out_size, void* d_ws, size_t ws_size,
                              hipStream_t stream) {
    const float* node_feats = (const float*)d_in[0];
    const float* edge_feats = (const float*)d_in[1];
    const float* degs       = (const float*)d_in[2];
    const float* norm       = (const float*)d_in[3];
    const int*   src        = (const int*)d_in[4];
    const int*   dst        = (const int*)d_in[5];
    const float* Wn         = (const float*)d_in[6];
    const float* bn         = (const float*)d_in[7];
    const float* We         = (const float*)d_in[8];
    const float* be         = (const float*)d_in[9];
    const float* res_w      = (const float*)d_in[10];

    float* out = (float*)d_out;

    // Workspace layout (bytes):
    //   h:      [0,        10240000)   N*D fp32
    //   perm:   [10240000, 12800000)   E i32
    //   dsts:   [12800000, 15360000)   E i32
    //   count:  [15360000, 15440000)   N i32 (scan in place; doubles as cursor)
    //   fragE:  [15500000, +32768)     We bf16 fragments
    //   fragH:  [15600000, +32768)     Wn hi fragments
    //   fragL:  [15700000, +32768)     Wn lo fragments
    //   bsum:   [15800000, +512)       scan chunk totals
    char* ws = (char*)d_ws;
    float*  h_ws  = (float*)(ws);
    int*    perm  = (int*)(ws + 10240000);
    int*    dsts  = (int*)(ws + 12800000);
    int*    count = (int*)(ws + 15360000);
    short8* fragE = (short8*)(ws + 15500000);
    short8* fragH = (short8*)(ws + 15600000);
    short8* fragL = (short8*)(ws + 15700000);
    int*    bsum  = (int*)(ws + 15800000);

    // Cooperative single-dispatch path; grid sized by occupancy API so
    // co-residency (required for grid.sync) is guaranteed.  MI355X: 256 CUs.
    int maxb = 0;
    const hipError_t oerr = hipOccupancyMaxActiveBlocksPerMultiprocessor(
        &maxb, reinterpret_cast<const void*>(mega_kernel), 256, 0);
    bool done = false;
    if (oerr == hipSuccess && maxb >= 1) {
        int gridb = maxb * 256;
        if (gridb > 2048) gridb = 2048;
        void* args[] = {
            (void*)&node_feats, (void*)&edge_feats, (void*)&degs, (void*)&norm,
            (void*)&src, (void*)&dst, (void*)&Wn, (void*)&bn, (void*)&We,
            (void*)&be, (void*)&res_w, (void*)&out, (void*)&h_ws,
            (void*)&perm, (void*)&dsts, (void*)&count, (void*)&bsum,
            (void*)&fragE, (void*)&fragH, (void*)&fragL };
        const hipError_t lerr = hipLaunchCooperativeKernel(
            reinterpret_cast<const void*>(mega_kernel),
            dim3(gridb), dim3(256), args, 0u, stream);
        done = (lerr == hipSuccess);
    }

    if (!done) {
        // Fallback: multi-dispatch structure.
        fb_prep<<<8, 256, 0, stream>>>(We, Wn, fragE, fragH, fragL, count);
        fb_hist<<<(N_EDGES + 255) / 256, 256, 0, stream>>>(dst, count);
        fb_scan<<<1, 256, 0, stream>>>(count);
        fb_scatter<<<(N_EDGES + 255) / 256, 256, 0, stream>>>(dst, count, perm, dsts);
        fb_node<<<N_TILES_NODE, 256, 0, stream>>>(node_feats, degs, fragH, fragL,
                                                  bn, res_w, h_ws, out);
        fb_edge<<<N_TILES_EDGE, 256, 0, stream>>>(edge_feats, norm, src, perm, dsts,
                                                  fragE, be, h_ws, out);
    }
}

// Round 4
// 634.760 us; speedup vs baseline: 1.7615x; 1.7615x over previous
//
#include <hip/hip_runtime.h>
#include <hip/hip_bf16.h>

// Problem constants (fixed by the reference file).
constexpr int N_NODES = 20000;
constexpr int N_EDGES = 640000;
constexpr int D = 128;          // D_IN == D_OUT == 128
constexpr int N_TILES_NODE = (N_NODES + 63) / 64;   // 313
constexpr int N_TILES_EDGE = N_EDGES / 128;         // 5000
constexpr int SCAT_BLOCKS  = (N_EDGES + 255) / 256; // 2500
constexpr int TILE_LD = 33;     // 32 m + 1 pad: conflict-free both ways

typedef float  f32x4  __attribute__((ext_vector_type(4)));
typedef short  short8 __attribute__((ext_vector_type(8)));

// fp32 -> bf16 bits, round-to-nearest-even (scalar)
__device__ inline short f2bf(float f) {
    unsigned u = __builtin_bit_cast(unsigned, f);
    u += 0x7fffu + ((u >> 16) & 1u);
    return (short)(u >> 16);
}
__device__ inline float bf2f(short s) {
    unsigned u = ((unsigned)(unsigned short)s) << 16;
    return __builtin_bit_cast(float, u);
}
// packed fp32x2 -> bf16x2 (RNE), single HW instruction
__device__ inline unsigned cvt_pk_bf16(float a, float b) {
    unsigned r;
    asm("v_cvt_pk_bf16_f32 %0, %1, %2" : "=v"(r) : "v"(a), "v"(b));
    return r;
}

// ---------------------------------------------------------------------------
// Prep: weight fragments (We -> fragE bf16; Wn -> fragH/fragL hi/lo split)
// + zero the counting-sort histogram.  Fragment index: frag[(nt*4+kt)*64 +
// lane], lane = quad*16 + row16, holding W[nt*16+row16][kt*32+quad*8+j].
// ---------------------------------------------------------------------------
__global__ __launch_bounds__(256) void prep_kernel(
    const float* __restrict__ We, const float* __restrict__ Wn,
    short8* __restrict__ fragE, short8* __restrict__ fragH,
    short8* __restrict__ fragL, int* __restrict__ count)
{
    const int t = blockIdx.x * 256 + threadIdx.x;   // 2048 threads
    for (int i = t; i < N_NODES; i += 2048) count[i] = 0;

    const int n = t >> 4, k8 = t & 15;
    const int kt = k8 >> 2, q = k8 & 3;
    const int fi = ((n >> 4) * 4 + kt) * 64 + q * 16 + (n & 15);

    {
        const float4 x = *(const float4*)(We + n * D + k8 * 8);
        const float4 y = *(const float4*)(We + n * D + k8 * 8 + 4);
        short8 s;
        unsigned* sp = (unsigned*)&s;
        sp[0] = cvt_pk_bf16(x.x, x.y);
        sp[1] = cvt_pk_bf16(x.z, x.w);
        sp[2] = cvt_pk_bf16(y.x, y.y);
        sp[3] = cvt_pk_bf16(y.z, y.w);
        fragE[fi] = s;
    }
    {
        const float4 x = *(const float4*)(Wn + n * D + k8 * 8);
        const float4 y = *(const float4*)(Wn + n * D + k8 * 8 + 4);
        const float v[8] = {x.x, x.y, x.z, x.w, y.x, y.y, y.z, y.w};
        short8 hi, lo;
        #pragma unroll
        for (int j = 0; j < 8; ++j) {
            hi[j] = f2bf(v[j]);
            lo[j] = f2bf(v[j] - bf2f(hi[j]));
        }
        fragH[fi] = hi;
        fragL[fi] = lo;
    }
}

// ---------------------------------------------------------------------------
// Counting sort: histogram, scan, scatter (scatter merged with node below).
// ---------------------------------------------------------------------------
__global__ __launch_bounds__(256) void hist_kernel(
    const int* __restrict__ dst, int* __restrict__ count)
{
    const int e = blockIdx.x * 256 + threadIdx.x;
    if (e < N_EDGES) atomicAdd(&count[dst[e]], 1);
}

__global__ __launch_bounds__(1024) void scan_kernel(
    const int* __restrict__ count, int* __restrict__ cursor)
{
    constexpr int PER = 20;                    // 1024*20 = 20480 >= 20000
    __shared__ int tot[1024];
    const int tid = threadIdx.x;
    const int base = tid * PER;

    int local[PER];
    int s = 0;
    #pragma unroll
    for (int i = 0; i < PER; ++i) {
        const int idx = base + i;
        const int v = (idx < N_NODES) ? count[idx] : 0;
        local[i] = s;
        s += v;
    }
    tot[tid] = s;
    __syncthreads();
    for (int off = 1; off < 1024; off <<= 1) {
        const int add = (tid >= off) ? tot[tid - off] : 0;
        __syncthreads();
        tot[tid] += add;
        __syncthreads();
    }
    const int excl = tot[tid] - s;
    #pragma unroll
    for (int i = 0; i < PER; ++i) {
        const int idx = base + i;
        if (idx < N_NODES) cursor[idx] = excl + local[i];
    }
}

// ---------------------------------------------------------------------------
// Node tile body: h = nf @ Wn.T + bn (hi/lo bf16 split, ~fp32 exact),
// h -> workspace; out = relu(h + res_w) / degs (residual init).
// ---------------------------------------------------------------------------
__device__ __forceinline__ void node_tile(
    int tb, int tid,
    const float* __restrict__ nf, const float* __restrict__ degs,
    const short8* __restrict__ fragH, const short8* __restrict__ fragL,
    const float* __restrict__ bn, const float* __restrict__ res_w,
    float* __restrict__ h_ws, float* __restrict__ out)
{
    const int lane = tid & 63, wave = tid >> 6;
    const int quad = lane >> 4, row16 = lane & 15;
    const int mbase = tb * 64 + wave * 16;

    const int arow = min(mbase + row16, N_NODES - 1);
    short8 ah[4], al[4];
    const float* p = nf + arow * D + quad * 8;
    #pragma unroll
    for (int kt = 0; kt < 4; ++kt) {
        const float4 x = *(const float4*)(p + kt * 32);
        const float4 y = *(const float4*)(p + kt * 32 + 4);
        const float v[8] = {x.x, x.y, x.z, x.w, y.x, y.y, y.z, y.w};
        #pragma unroll
        for (int j = 0; j < 8; ++j) {
            ah[kt][j] = f2bf(v[j]);
            al[kt][j] = f2bf(v[j] - bf2f(ah[kt][j]));
        }
    }

    int   orow[4];
    float dinv[4];
    #pragma unroll
    for (int r = 0; r < 4; ++r) {
        orow[r] = mbase + quad * 4 + r;
        dinv[r] = 1.0f / degs[min(orow[r], N_NODES - 1)];
    }

    #pragma unroll
    for (int nt = 0; nt < 8; ++nt) {
        f32x4 acc = {0.f, 0.f, 0.f, 0.f};
        #pragma unroll
        for (int kt = 0; kt < 4; ++kt) {
            const short8 bh = fragH[(nt * 4 + kt) * 64 + lane];
            const short8 bl = fragL[(nt * 4 + kt) * 64 + lane];
            acc = __builtin_amdgcn_mfma_f32_16x16x32_bf16(al[kt], bh, acc, 0, 0, 0);
            acc = __builtin_amdgcn_mfma_f32_16x16x32_bf16(ah[kt], bl, acc, 0, 0, 0);
            acc = __builtin_amdgcn_mfma_f32_16x16x32_bf16(ah[kt], bh, acc, 0, 0, 0);
        }
        const int col = nt * 16 + row16;
        const float bnv = bn[col], rwv = res_w[col];
        #pragma unroll
        for (int r = 0; r < 4; ++r) {
            if (orow[r] < N_NODES) {
                const float hv = acc[r] + bnv;
                h_ws[orow[r] * D + col] = hv;
                out[orow[r] * D + col] = fmaxf(hv + rwv, 0.0f) * dinv[r];
            }
        }
    }
}

// ---------------------------------------------------------------------------
// Mid kernel: node tiles (blocks [0, N_TILES_NODE)) + scatter (rest).
// Independent work merged into one dispatch so scatter's atomic/store latency
// hides under node's MFMA.  Scatter writes ONE 8B int2 (perm,dst) per edge.
// ---------------------------------------------------------------------------
__global__ __launch_bounds__(256) void mid_kernel(
    const int* __restrict__ dst, int* __restrict__ cursor,
    int2* __restrict__ pd,
    const float* __restrict__ nf, const float* __restrict__ degs,
    const short8* __restrict__ fragH, const short8* __restrict__ fragL,
    const float* __restrict__ bn, const float* __restrict__ res_w,
    float* __restrict__ h_ws, float* __restrict__ out)
{
    if (blockIdx.x < N_TILES_NODE) {
        node_tile(blockIdx.x, threadIdx.x, nf, degs, fragH, fragL,
                  bn, res_w, h_ws, out);
    } else {
        const int e = (blockIdx.x - N_TILES_NODE) * 256 + threadIdx.x;
        if (e < N_EDGES) {
            const int d = dst[e];
            const int pos = atomicAdd(&cursor[d], 1);
            pd[pos] = make_int2(e, d);
        }
    }
}

// ---------------------------------------------------------------------------
// Edge kernel: edges in dst-sorted order (pd = packed perm,dst).
//   e   = ef[perm] @ We.T + be   (bf16 MFMA, B-fragments from global fragE)
//   msg = norm * relu(h[src] + e)
//   segmented sum over sorted-dst runs; one atomic per run per column.
// Wave-private tile/sdst (in-order DS pipe), no __syncthreads.  g-loop fully
// unrolled; h gathers issued before the group's MFMAs so their LLC latency
// hides under the matrix work; perm indices come from __shfl of pd regs.
// ---------------------------------------------------------------------------
__global__ __launch_bounds__(256) void edge_kernel(
    const float* __restrict__ ef, const float* __restrict__ norm,
    const int* __restrict__ src, const int2* __restrict__ pd,
    const short8* __restrict__ fragE, const float* __restrict__ be,
    const float* __restrict__ h, float* __restrict__ out)
{
    __shared__ float tile[4][32 * TILE_LD]; // 16896 B: per-wave [c][m]
    __shared__ int   sdst[4][32];           // 512 B

    const int t = threadIdx.x;
    const int lane  = t & 63;
    const int quad  = lane >> 4;
    const int row16 = lane & 15;
    const int wave  = t >> 6;
    const int p0 = blockIdx.x * 128 + wave * 32;   // 32 sorted positions/wave

    int2 pdv = make_int2(0, 0);
    if (lane < 32) {
        pdv = pd[p0 + lane];
        sdst[wave][lane] = pdv.y;
    }

    // ---- A fragments: perm via cross-lane shfl, gather edge rows, fp32->bf16
    short8 afr[2][4];
    #pragma unroll
    for (int mt = 0; mt < 2; ++mt) {
        const int erow = __shfl(pdv.x, mt * 16 + row16, 64);
        const float* p = ef + erow * D + quad * 8;
        #pragma unroll
        for (int kt = 0; kt < 4; ++kt) {
            const float4 x = *(const float4*)(p + kt * 32);
            const float4 y = *(const float4*)(p + kt * 32 + 4);
            short8 a;
            unsigned* ap = (unsigned*)&a;
            ap[0] = cvt_pk_bf16(x.x, x.y);
            ap[1] = cvt_pk_bf16(x.z, x.w);
            ap[2] = cvt_pk_bf16(y.x, y.y);
            ap[3] = cvt_pk_bf16(y.z, y.w);
            afr[mt][kt] = a;
        }
    }

    // ---- Edge metadata for the epilogue rows this lane owns
    int   sidx[2][4];
    float nrm[2][4];
    #pragma unroll
    for (int mt = 0; mt < 2; ++mt) {
        #pragma unroll
        for (int r = 0; r < 4; ++r) {
            const int pe = __shfl(pdv.x, mt * 16 + quad * 4 + r, 64);
            sidx[mt][r] = src[pe];
            nrm[mt][r]  = norm[pe];
        }
    }

    float* tw = &tile[wave][0];
    const int* sw = &sdst[wave][0];

    #pragma unroll
    for (int g = 0; g < 4; ++g) {
        // (1) h prefetch for this group's two 16-col tiles (issued early;
        //     latency overlaps the MFMAs below)
        float hv[2][2][4];
        #pragma unroll
        for (int t2 = 0; t2 < 2; ++t2)
            #pragma unroll
            for (int mt = 0; mt < 2; ++mt)
                #pragma unroll
                for (int r = 0; r < 4; ++r)
                    hv[t2][mt][r] = h[sidx[mt][r] * D + (g * 2 + t2) * 16 + row16];

        // (2) MFMA both column tiles
        f32x4 acc[2][2];
        #pragma unroll
        for (int t2 = 0; t2 < 2; ++t2) {
            const int nt = g * 2 + t2;
            short8 bfr[4];
            #pragma unroll
            for (int kt = 0; kt < 4; ++kt)
                bfr[kt] = fragE[(nt * 4 + kt) * 64 + lane];
            f32x4 a0 = {0.f, 0.f, 0.f, 0.f};
            f32x4 a1 = {0.f, 0.f, 0.f, 0.f};
            #pragma unroll
            for (int kt = 0; kt < 4; ++kt) {
                a0 = __builtin_amdgcn_mfma_f32_16x16x32_bf16(afr[0][kt], bfr[kt], a0, 0, 0, 0);
                a1 = __builtin_amdgcn_mfma_f32_16x16x32_bf16(afr[1][kt], bfr[kt], a1, 0, 0, 0);
            }
            acc[t2][0] = a0;
            acc[t2][1] = a1;
        }

        // (3) epilogue: msg = norm * relu(h + e + be) -> LDS tile [c][m]
        #pragma unroll
        for (int t2 = 0; t2 < 2; ++t2) {
            const int col = (g * 2 + t2) * 16 + row16;
            const float bev = be[col];
            float* tp = tw + (t2 * 16 + row16) * TILE_LD;
            #pragma unroll
            for (int r = 0; r < 4; ++r) {
                const int m0 = quad * 4 + r;
                tp[m0]      = nrm[0][r] * fmaxf(hv[t2][0][r] + acc[t2][0][r] + bev, 0.0f);
                tp[m0 + 16] = nrm[1][r] * fmaxf(hv[t2][1][r] + acc[t2][1][r] + bev, 0.0f);
            }
        }

        // (4) segmented scan: lane = c*2 + chunk; chunk covers 16 sorted rows.
        //     (wave-private LDS: in-order DS pipe orders writes vs reads)
        {
            const int c = lane >> 1;
            const int mbeg = (lane & 1) * 16;
            const float* sp = tw + c * TILE_LD;
            const int gcol = g * 32 + c;
            int cur = sw[mbeg];
            float sum = 0.0f;
            #pragma unroll
            for (int m = mbeg; m < mbeg + 16; ++m) {
                const int dm = sw[m];
                const float v = sp[m];
                if (dm != cur) {
                    atomicAdd(&out[cur * D + gcol], sum);
                    sum = 0.0f;
                    cur = dm;
                }
                sum += v;
            }
            atomicAdd(&out[cur * D + gcol], sum);
        }
    }
}

extern "C" void kernel_launch(void* const* d_in, const int* in_sizes, int n_in,
                              void* d_out, int out_size, void* d_ws, size_t ws_size,
                              hipStream_t stream) {
    const float* node_feats = (const float*)d_in[0];
    const float* edge_feats = (const float*)d_in[1];
    const float* degs       = (const float*)d_in[2];
    const float* norm       = (const float*)d_in[3];
    const int*   src        = (const int*)d_in[4];
    const int*   dst        = (const int*)d_in[5];
    const float* Wn         = (const float*)d_in[6];
    const float* bn         = (const float*)d_in[7];
    const float* We         = (const float*)d_in[8];
    const float* be         = (const float*)d_in[9];
    const float* res_w      = (const float*)d_in[10];

    float* out = (float*)d_out;

    // Workspace layout (bytes):
    //   h:      [0,        10240000)   N*D fp32
    //   pd:     [10240000, 15360000)   E int2 (perm, dst) packed
    //   count:  [15360000, 15440000)   N i32 (scan in place; doubles as cursor)
    //   fragE:  [15500000, +32768)     We bf16 fragments
    //   fragH:  [15600000, +32768)     Wn hi fragments
    //   fragL:  [15700000, +32768)     Wn lo fragments
    char* ws = (char*)d_ws;
    float*  h_ws  = (float*)(ws);
    int2*   pd    = (int2*)(ws + 10240000);
    int*    count = (int*)(ws + 15360000);
    short8* fragE = (short8*)(ws + 15500000);
    short8* fragH = (short8*)(ws + 15600000);
    short8* fragL = (short8*)(ws + 15700000);

    // 0) weight fragments + histogram zero
    prep_kernel<<<8, 256, 0, stream>>>(We, Wn, fragE, fragH, fragL, count);

    // 1) histogram + scan
    hist_kernel<<<SCAT_BLOCKS, 256, 0, stream>>>(dst, count);
    scan_kernel<<<1, 1024, 0, stream>>>(count, count);

    // 2) node path + scatter, merged (independent work, one dispatch)
    mid_kernel<<<N_TILES_NODE + SCAT_BLOCKS, 256, 0, stream>>>(
        dst, count, pd, node_feats, degs, fragH, fragL, bn, res_w, h_ws, out);

    // 3) edge path: sorted-order GEMM + segmented-sum aggregation
    edge_kernel<<<N_TILES_EDGE, 256, 0, stream>>>(edge_feats, norm, src, pd,
                                                  fragE, be, h_ws, out);
}